// Round 15
// baseline (290.105 us; speedup 1.0000x reference)
//
#include <hip/hip_runtime.h>
#include <hip/hip_bf16.h>

#define BB 8
#define NN 4096
#define FF 64
#define HH 128
#define KNN 16

typedef __attribute__((ext_vector_type(8))) short bf16x8;
typedef __attribute__((ext_vector_type(4))) float f32x4;

// Fragment-ordered bf16 weight workspace offsets (in shorts)
#define OFF_iW2 0
#define OFF_fW1 16384
#define OFF_fW2 24576
#define OFF_sW1 40960
#define OFF_sW2 73728
#define HI_SZ   90112

// ---- reference-matching arithmetic (XLA-CPU style: FMA-contracted dot/sq) ----
__device__ __forceinline__ float sq3(float x, float y, float z) {
    return fmaf(z, z, fmaf(y, y, __fmul_rn(x, x)));
}
__device__ __forceinline__ float dist2f(float px, float py, float pz, float psq, float4 cc) {
    float t = fmaf(pz, cc.z, fmaf(py, cc.y, __fmul_rn(px, cc.x)));
    return __fsub_rn(__fadd_rn(psq, cc.w), __fmul_rn(2.0f, t));
}

// round-to-nearest-even f32 -> bf16 bits (finite inputs)
__device__ __forceinline__ short f2bf(float x) {
    unsigned u = __float_as_uint(x);
    u += 0x7fffu + ((u >> 16) & 1u);
    return (short)(u >> 16);
}
__device__ __forceinline__ float bf2f(short s) {
    return __uint_as_float(((unsigned)(unsigned short)s) << 16);
}

// ---------------- Kernel 1: pack coords + sq norm, per-batch center ----------------
extern "C" __global__ __launch_bounds__(256)
void k_prep(const float* __restrict__ coords, float4* __restrict__ coords4, float* __restrict__ center) {
    const int b = blockIdx.x, tid = threadIdx.x;
    __shared__ float rx[256], ry[256], rz[256];
    float sx = 0.f, sy = 0.f, sz = 0.f;
    for (int n = tid; n < NN; n += 256) {
        const float* c = coords + (size_t)(b * NN + n) * 3;
        float x = c[0], y = c[1], z = c[2];
        coords4[b * NN + n] = make_float4(x, y, z, sq3(x, y, z));
        sx += x; sy += y; sz += z;
    }
    rx[tid] = sx; ry[tid] = sy; rz[tid] = sz;
    __syncthreads();
    for (int s = 128; s > 0; s >>= 1) {
        if (tid < s) { rx[tid] += rx[tid + s]; ry[tid] += ry[tid + s]; rz[tid] += rz[tid + s]; }
        __syncthreads();
    }
    if (tid == 0) {
        center[b * 4 + 0] = rx[0] * (1.0f / NN);
        center[b * 4 + 1] = ry[0] * (1.0f / NN);
        center[b * 4 + 2] = rz[0] * (1.0f / NN);
    }
}

// ---------------- Kernel 1b: split weights into hi/lo bf16, MFMA-fragment-ordered ----------------
extern "C" __global__ __launch_bounds__(256)
void k_wprep(const float* __restrict__ iW2, const float* __restrict__ fW1,
             const float* __restrict__ fW2, const float* __restrict__ sW1,
             const float* __restrict__ sW2, short* __restrict__ wbf) {
    const int w = blockIdx.y;
    const float* W; int K; int off;
    if (w == 0)      { W = iW2; K = 128; off = OFF_iW2; }
    else if (w == 1) { W = fW1; K = 64;  off = OFF_fW1; }
    else if (w == 2) { W = fW2; K = 128; off = OFF_fW2; }
    else if (w == 3) { W = sW1; K = 256; off = OFF_sW1; }
    else             { W = sW2; K = 128; off = OFF_sW2; }
    short* hi = wbf + off;
    short* lo = wbf + HI_SZ + off;
    const int total = K * 128;
    for (int e = blockIdx.x * 256 + threadIdx.x; e < total; e += gridDim.x * 256) {
        int j = e & 7, lane = (e >> 3) & 63, ct = (e >> 9) & 7, kb = e >> 12;
        int k = kb * 32 + (lane >> 4) * 8 + j;
        int n = ct * 16 + (lane & 15);
        float v = W[k * 128 + n];
        short h = f2bf(v);
        float r = v - bf2f(h);
        hi[e] = h; lo[e] = f2bf(r);
    }
}

// Jacobi rotation on symmetric 3x3 (exact rotations, division-safe).
#define JROT(app, aqq, apq, arp, arq, vp0, vp1, vp2, vq0, vq1, vq2) { \
    float tau_ = (aqq - app) / (2.0f * apq); \
    float tt_ = copysignf(1.0f, tau_) / (fabsf(tau_) + sqrtf(1.0f + tau_ * tau_)); \
    if (apq == 0.0f) tt_ = 0.0f; \
    float cc_ = 1.0f / sqrtf(1.0f + tt_ * tt_); \
    float ss_ = tt_ * cc_; \
    float app_n = cc_*cc_*app - 2.0f*cc_*ss_*apq + ss_*ss_*aqq; \
    float aqq_n = ss_*ss_*app + 2.0f*cc_*ss_*apq + cc_*cc_*aqq; \
    float apq_n = cc_*ss_*(app - aqq) + (cc_*cc_ - ss_*ss_)*apq; \
    float arp_n = cc_*arp - ss_*arq; \
    float arq_n = ss_*arp + cc_*arq; \
    app = app_n; aqq = aqq_n; apq = apq_n; arp = arp_n; arq = arq_n; \
    float t0_ = cc_*vp0 - ss_*vq0, t1_ = cc_*vp1 - ss_*vq1, t2_ = cc_*vp2 - ss_*vq2; \
    vq0 = ss_*vp0 + cc_*vq0; vq1 = ss_*vp1 + cc_*vq1; vq2 = ss_*vp2 + cc_*vq2; \
    vp0 = t0_; vp1 = t1_; vp2 = t2_; }

#define SWAPF(a, b) { float sw_ = a; a = b; b = sw_; }

// Bitonic sort 16 floats ascending.
__device__ __forceinline__ void sort16(float (&d)[16]) {
#pragma unroll
    for (int k = 2; k <= 16; k <<= 1) {
#pragma unroll
        for (int j = k >> 1; j > 0; j >>= 1) {
#pragma unroll
            for (int i = 0; i < 16; i++) {
                int l = i ^ j;
                if (l > i) {
                    if ((i & k) == 0) {
                        float mn = fminf(d[i], d[l]);
                        d[l] = fmaxf(d[i], d[l]);
                        d[i] = mn;
                    } else {
                        float mx = fmaxf(d[i], d[l]);
                        d[l] = fminf(d[i], d[l]);
                        d[i] = mx;
                    }
                }
            }
        }
    }
}

// dk (asc) + d (asc) -> dk = 16 smallest of the 32, ascending.
__device__ __forceinline__ void merge16(float (&dk)[16], const float (&d)[16]) {
    float t[16];
#pragma unroll
    for (int i = 0; i < 16; i++) t[i] = fminf(dk[i], d[15 - i]);
#pragma unroll
    for (int j = 8; j > 0; j >>= 1) {
#pragma unroll
        for (int i = 0; i < 16; i++) {
            int l = i ^ j;
            if (l > i) {
                float mn = fminf(t[i], t[l]);
                t[l] = fmaxf(t[i], t[l]);
                t[i] = mn;
            }
        }
    }
#pragma unroll
    for (int i = 0; i < 16; i++) dk[i] = t[i];
}

// ---------------- MLP helpers ----------------
__device__ __forceinline__ float gelu_exact(float x) {
    return 0.5f * x * (1.0f + erff(x * 0.70710678118654752440f));
}

// Small-K GEMM (K=6), f32 VALU.
template <int KDIM, int LDA>
__device__ __forceinline__ void gemm_small(const float* A, const float* __restrict__ W,
                                           const float* __restrict__ bias, int p0, int c0, float acc[4][4]) {
    float4 bb = *(const float4*)(bias + c0);
#pragma unroll
    for (int i = 0; i < 4; i++) { acc[i][0] = bb.x; acc[i][1] = bb.y; acc[i][2] = bb.z; acc[i][3] = bb.w; }
#pragma unroll
    for (int k = 0; k < KDIM; k++) {
        float4 w = *(const float4*)(W + k * HH + c0);
#pragma unroll
        for (int i = 0; i < 4; i++) {
            float a = A[(p0 + i) * LDA + k];
            acc[i][0] = fmaf(a, w.x, acc[i][0]);
            acc[i][1] = fmaf(a, w.y, acc[i][1]);
            acc[i][2] = fmaf(a, w.z, acc[i][2]);
            acc[i][3] = fmaf(a, w.w, acc[i][3]);
        }
    }
}

// MFMA GEMM: C[32][128] += A[32][K] @ W[K][128], A bf16 LDS [32][136], W hi+lo exact split.
template <int KB, bool INIT>
__device__ __forceinline__ void gemm_mfma(const short* Ab, const short* __restrict__ whi,
                                          const short* __restrict__ wlo,
                                          const float* __restrict__ bias,
                                          int wid, int lane, f32x4 acc[2][2]) {
    const int m16 = lane & 15, quad = lane >> 4;
    if (INIT) {
        float b0 = bias[(wid * 2 + 0) * 16 + m16];
        float b1 = bias[(wid * 2 + 1) * 16 + m16];
        acc[0][0] = (f32x4){b0, b0, b0, b0}; acc[1][0] = acc[0][0];
        acc[0][1] = (f32x4){b1, b1, b1, b1}; acc[1][1] = acc[0][1];
    }
#pragma unroll 1
    for (int kb = 0; kb < KB; kb++) {
        bf16x8 a0 = *(const bf16x8*)(Ab + m16 * 136 + kb * 32 + quad * 8);
        bf16x8 a1 = *(const bf16x8*)(Ab + (m16 + 16) * 136 + kb * 32 + quad * 8);
#pragma unroll
        for (int c = 0; c < 2; c++) {
            const int off = ((kb * 8 + wid * 2 + c) * 64 + lane) * 8;
            bf16x8 bh = *(const bf16x8*)(whi + off);
            bf16x8 bl = *(const bf16x8*)(wlo + off);
            acc[0][c] = __builtin_amdgcn_mfma_f32_16x16x32_bf16(a0, bh, acc[0][c], 0, 0, 0);
            acc[0][c] = __builtin_amdgcn_mfma_f32_16x16x32_bf16(a0, bl, acc[0][c], 0, 0, 0);
            acc[1][c] = __builtin_amdgcn_mfma_f32_16x16x32_bf16(a1, bh, acc[1][c], 0, 0, 0);
            acc[1][c] = __builtin_amdgcn_mfma_f32_16x16x32_bf16(a1, bl, acc[1][c], 0, 0, 0);
        }
    }
}

// acc (C-layout) -> gelu? -> bf16 directly into operand buffer [32][136].
// (Every consumer is a following MFMA, so the f32 staging round-trip is redundant —
//  same rounding path as before, minus 16 KB LDS and its write+read.)
__device__ __forceinline__ void acc_to_bf(short* dst, f32x4 acc[2][2], int wid, int lane, bool dogelu) {
    const int m16 = lane & 15, quad = lane >> 4;
#pragma unroll
    for (int mt = 0; mt < 2; mt++)
#pragma unroll
        for (int c = 0; c < 2; c++)
#pragma unroll
            for (int i = 0; i < 4; i++) {
                float v = acc[mt][c][i];
                if (dogelu) v = gelu_exact(v);
                dst[(mt * 16 + quad * 4 + i) * 136 + (wid * 2 + c) * 16 + m16] = f2bf(v);
            }
}

// ---------------- Fused kernel: kNN + geometry + MFMA MLP per 32-point block ----------------
// LDS 22.1 KB -> 7 blocks/CU (was 35.3 KB -> 4): ilist in shorts, fstage removed.
extern "C" __global__ __launch_bounds__(256, 7)
void k_fused(const float4* __restrict__ coords4, const float* __restrict__ center,
             const float* __restrict__ features, const short* __restrict__ wbf,
             const float* __restrict__ iW1, const float* __restrict__ ib1,
             const float* __restrict__ ib2,
             const float* __restrict__ fb1, const float* __restrict__ fb2,
             const float* __restrict__ sb1, const float* __restrict__ sb2,
             const float* __restrict__ gW, const float* __restrict__ gb,
             float* __restrict__ out) {
    const int blk = blockIdx.x;
    const int b = blk >> 7;
    const int chunk = blk & 127;
    const int tid = threadIdx.x;
    const int pid = tid & 31;
    const int h = tid >> 5;
    const int n = chunk * 32 + pid;
    const float4* __restrict__ C = coords4 + b * NN;

    __shared__ __align__(16) char smem[22144];
    float4* tile = (float4*)smem;                  // 8 KB          (phase 1)
    short* ilist = (short*)(smem + 8192);          // 256*23*2 = 11776 (phase 1; idx < 4096)
    int* cnts = (int*)(smem + 19968);              // 1 KB
    float* inv8 = (float*)(smem + 20992);          // 1 KB          (epilogue -> phase 2)
    float* sc = (float*)(smem + 22016);            // 128 B
    float* mb = (float*)smem;                      // merge buf 17408 B, aliases tile+ilist (dead)
    // phase-2 aliases (tile/ilist/cnts dead):
    short* Abf = (short*)smem;                     // [32][136] bf16, 8704 B
    short* FHbf = (short*)(smem + 8704);           // [32][136] bf16, 8704 B (ends 17408)

    float4 me = C[n];
    const float px = me.x, py = me.y, pz = me.z, psq = me.w;
    const float INF = __builtin_inff();

    // ======== PHASE 1: kNN (bitwise identical selection algebra) ========
    float dk[KNN];
#pragma unroll
    for (int i = 0; i < KNN; i++) dk[i] = INF;

    for (int r = 0; r < 8; r++) {
        __syncthreads();
#pragma unroll
        for (int e = tid; e < 512; e += 256) {
            int seg = e >> 6, idx = e & 63;
            tile[e] = C[seg * 512 + r * 64 + idx];
        }
        __syncthreads();
        const float4* T = &tile[h * 64];
        const int selfj = n - (h * 512 + r * 64);
#pragma unroll
        for (int bt = 0; bt < 4; bt++) {
            float d[16];
#pragma unroll
            for (int i = 0; i < 16; i++) {
                float4 cc = T[bt * 16 + i];
                float dd = dist2f(px, py, pz, psq, cc);
                d[i] = (bt * 16 + i) == selfj ? INF : dd;
            }
            sort16(d);
            merge16(dk, d);
        }
    }

    __syncthreads();
#pragma unroll
    for (int i = 0; i < KNN; i++) mb[tid * 17 + i] = dk[i];
    __syncthreads();
#pragma unroll
    for (int p = 1; p < 8; p++) {
        const int partner = (((h + p) & 7) << 5) + pid;
        float o[16];
#pragma unroll
        for (int i = 0; i < KNN; i++) o[i] = mb[partner * 17 + i];
        merge16(dk, o);
    }
    const float d15 = dk[15];

    int cs = 0, ct = 0;
    const int lbase = (pid * 8 + h) * 23;
    for (int r = 0; r < 8; r++) {
        __syncthreads();
#pragma unroll
        for (int e = tid; e < 512; e += 256) {
            int seg = e >> 6, idx = e & 63;
            tile[e] = C[seg * 512 + r * 64 + idx];
        }
        __syncthreads();
        const float4* T = &tile[h * 64];
        const int base = h * 512 + r * 64;
#pragma unroll 4
        for (int j = 0; j < 64; j++) {
            float4 cc = T[j];
            float d = dist2f(px, py, pz, psq, cc);   // bitwise identical to pass 1
            int g = base + j;
            if (g != n && d <= d15) {
                if (d < d15) {
                    if (cs < 15) ilist[lbase + cs] = (short)g;
                    cs++;
                } else if (ct < 8) {
                    ilist[lbase + 15 + ct] = (short)g;
                    ct++;
                }
            }
        }
    }
    cnts[pid * 8 + h] = (cs & 0xff) | (ct << 8);
    __syncthreads();

    // ======== epilogue: geometry (threads 0..31) ========
    if (h == 0) {
        int s[8], t8[8], sb[8], tb[8], cum[8], tcum[8];
#pragma unroll
        for (int q = 0; q < 8; q++) {
            int cp = cnts[pid * 8 + q];
            s[q] = cp & 0xff; t8[q] = cp >> 8;
            sb[q] = (pid * 8 + q) * 23; tb[q] = sb[q] + 15;
        }
        cum[0] = s[0]; tcum[0] = t8[0];
#pragma unroll
        for (int q = 1; q < 8; q++) { cum[q] = cum[q - 1] + s[q]; tcum[q] = tcum[q - 1] + t8[q]; }

        float cxx = 0.f, cxy = 0.f, cxz = 0.f, cyy = 0.f, cyz = 0.f, czz = 0.f, radsum = 0.f;
#pragma unroll
        for (int j = 0; j < KNN; j++) {
            int addr = sb[0] + j;
#pragma unroll
            for (int q = 1; q < 8; q++)
                if (j >= cum[q - 1]) addr = sb[q] + (j - cum[q - 1]);
            int jt = j - cum[7];
            if (j >= cum[7]) addr = tb[0] + jt;
#pragma unroll
            for (int q = 1; q < 8; q++)
                if (j >= cum[7] && jt >= tcum[q - 1]) addr = tb[q] + (jt - tcum[q - 1]);
            int id = ilist[addr];
            float4 cc = C[id];
            float rx = __fsub_rn(cc.x, px), ry = __fsub_rn(cc.y, py), rz = __fsub_rn(cc.z, pz);
            cxx = __fadd_rn(cxx, __fmul_rn(rx, rx));
            cxy = __fadd_rn(cxy, __fmul_rn(rx, ry));
            cxz = __fadd_rn(cxz, __fmul_rn(rx, rz));
            cyy = __fadd_rn(cyy, __fmul_rn(ry, ry));
            cyz = __fadd_rn(cyz, __fmul_rn(ry, rz));
            czz = __fadd_rn(czz, __fmul_rn(rz, rz));
            float rr = __fadd_rn(__fadd_rn(__fmul_rn(rx, rx), __fmul_rn(ry, ry)), __fmul_rn(rz, rz));
            radsum = __fadd_rn(radsum, sqrtf(rr));
        }
        const float inv_k = 1.0f / KNN;
        float a00 = cxx * inv_k, a01 = cxy * inv_k, a02 = cxz * inv_k;
        float a11 = cyy * inv_k, a12 = cyz * inv_k, a22 = czz * inv_k;

        float V00 = 1.f, V01 = 0.f, V02 = 0.f;
        float V10 = 0.f, V11 = 1.f, V12 = 0.f;
        float V20 = 0.f, V21 = 0.f, V22 = 1.f;
        for (int sweep = 0; sweep < 6; sweep++) {
            JROT(a00, a11, a01, a02, a12, V00, V10, V20, V01, V11, V21);
            JROT(a00, a22, a02, a01, a12, V00, V10, V20, V02, V12, V22);
            JROT(a11, a22, a12, a01, a02, V01, V11, V21, V02, V12, V22);
        }
        float e0 = a00, e1 = a11, e2 = a22;
        float x0 = V00, y0 = V10, z0 = V20;
        float x1 = V01, y1 = V11, z1 = V21;
        float x2 = V02, y2 = V12, z2 = V22;
        if (e0 > e1) { SWAPF(e0, e1); SWAPF(x0, x1); SWAPF(y0, y1); SWAPF(z0, z1); }
        if (e1 > e2) { SWAPF(e1, e2); SWAPF(x1, x2); SWAPF(y1, y2); SWAPF(z1, z2); }
        if (e0 > e1) { SWAPF(e0, e1); SWAPF(x0, x1); SWAPF(y0, y1); SWAPF(z0, z1); }

        float cx = center[b * 4 + 0], cy = center[b * 4 + 1], cz = center[b * 4 + 2];
        float ox = __fsub_rn(px, cx), oy = __fsub_rn(py, cy), oz = __fsub_rn(pz, cz);
        float dt = __fadd_rn(__fadd_rn(__fmul_rn(x0, ox), __fmul_rn(y0, oy)), __fmul_rn(z0, oz));
        float sgn = (dt >= 0.0f) ? 1.0f : -1.0f;
        x0 *= sgn; y0 *= sgn; z0 *= sgn;
        float nrm = sqrtf(__fadd_rn(__fadd_rn(__fmul_rn(x0, x0), __fmul_rn(y0, y0)), __fmul_rn(z0, z0)));
        float den = fmaxf(nrm, 1e-6f);
        x0 = x0 / den; y0 = y0 / den; z0 = z0 / den;

        float radius = radsum * inv_k;
        float crad = sqrtf(__fadd_rn(__fadd_rn(__fmul_rn(ox, ox), __fmul_rn(oy, oy)), __fmul_rn(oz, oz)));
        float esum = fmaxf(__fadd_rn(__fadd_rn(e0, e1), e2), 1e-6f);
        float dom = e2 / esum;

        float* ip = inv8 + pid * 8;
        ip[0] = e0; ip[1] = e1; ip[2] = e2; ip[3] = radius; ip[4] = crad; ip[5] = dom;
        ip[6] = 0.f; ip[7] = 0.f;

        float pd = __fadd_rn(__fadd_rn(__fmul_rn(px, x0), __fmul_rn(py, y0)), __fmul_rn(pz, z0));
        float4* o = (float4*)(out + (size_t)(b * NN + n) * 16);
        o[0] = make_float4(0.0f, x0, y0, -z0);
        o[1] = make_float4(-pd, x0, y0, z0);
        o[2] = make_float4(0.0f, 0.0f, 0.0f, px);
        o[3] = make_float4(py, pz, 1.0f, 0.0f);
        sc[pid] = gb[0];
    }
    __syncthreads();   // phase boundary: tile/ilist/cnts dead; inv8/sc live

    // ======== PHASE 2: MFMA MLP (direct bf16 staging, no f32 round-trip) ========
    const int wid = tid >> 6, lane = tid & 63;
    const short* w_iW2h = wbf + OFF_iW2; const short* w_iW2l = wbf + HI_SZ + OFF_iW2;
    const short* w_fW1h = wbf + OFF_fW1; const short* w_fW1l = wbf + HI_SZ + OFF_fW1;
    const short* w_fW2h = wbf + OFF_fW2; const short* w_fW2l = wbf + HI_SZ + OFF_fW2;
    const short* w_sW1h = wbf + OFF_sW1; const short* w_sW1l = wbf + HI_SZ + OFF_sW1;
    const short* w_sW2h = wbf + OFF_sW2; const short* w_sW2l = wbf + HI_SZ + OFF_sW2;
    f32x4 acc[2][2];

    // s1: features (32 x 64) -> Abf bf16
    {
        int row = tid >> 3, c8 = (tid & 7) * 8;
        const float* s = features + (size_t)(b * NN + chunk * 32 + row) * FF + c8;
        float4 v0 = *(const float4*)s, v1 = *(const float4*)(s + 4);
        bf16x8 pk;
        pk[0] = f2bf(v0.x); pk[1] = f2bf(v0.y); pk[2] = f2bf(v0.z); pk[3] = f2bf(v0.w);
        pk[4] = f2bf(v1.x); pk[5] = f2bf(v1.y); pk[6] = f2bf(v1.z); pk[7] = f2bf(v1.w);
        *(bf16x8*)(Abf + row * 136 + c8) = pk;
    }
    __syncthreads();

    // s2: L1b = gelu(feat @ fW1 + fb1) -> Abf (in place; read-drain barrier first)
    gemm_mfma<2, true>(Abf, w_fW1h, w_fW1l, fb1, wid, lane, acc);
    __syncthreads();
    acc_to_bf(Abf, acc, wid, lane, true);
    __syncthreads();

    // s4: L2b = (h @ fW2 + fb2) -> feat_h -> FHbf
    gemm_mfma<4, true>(Abf, w_fW2h, w_fW2l, fb2, wid, lane, acc);
    __syncthreads();
    acc_to_bf(FHbf, acc, wid, lane, false);
    __syncthreads();

    // s6: L1a = gelu(inv @ iW1 + ib1)  (K=6, VALU) -> Abf direct
    {
        const int cg = tid & 31, pg = tid >> 5;
        const int c0 = cg * 4, p0 = pg * 4;
        float a4[4][4];
        gemm_small<6, 8>(inv8, iW1, ib1, p0, c0, a4);
#pragma unroll
        for (int i = 0; i < 4; i++)
#pragma unroll
            for (int j = 0; j < 4; j++)
                Abf[(p0 + i) * 136 + c0 + j] = f2bf(gelu_exact(a4[i][j]));
    }
    __syncthreads();

    // s8: L2a = (h @ iW2 + ib2) -> inv_h -> Abf
    gemm_mfma<4, true>(Abf, w_iW2h, w_iW2l, ib2, wid, lane, acc);
    __syncthreads();
    acc_to_bf(Abf, acc, wid, lane, false);
    __syncthreads();

    // s10: L1c = gelu(concat(inv_h, feat_h) @ sW1 + sb1)  (two-stage K=128+128)
    gemm_mfma<4, true>(Abf, w_sW1h, w_sW1l, sb1, wid, lane, acc);
    gemm_mfma<4, false>(FHbf, w_sW1h + 16384, w_sW1l + 16384, nullptr, wid, lane, acc);
    __syncthreads();
    acc_to_bf(Abf, acc, wid, lane, true);
    __syncthreads();

    // s12: L2c = (h @ sW2 + sb2); scalar = hidden @ gW + gb
    gemm_mfma<4, true>(Abf, w_sW2h, w_sW2l, sb2, wid, lane, acc);
    {
        const int m16 = lane & 15, quad = lane >> 4;
#pragma unroll
        for (int mt = 0; mt < 2; mt++)
#pragma unroll
            for (int c = 0; c < 2; c++) {
                float g = gW[(wid * 2 + c) * 16 + m16];
#pragma unroll
                for (int i = 0; i < 4; i++)
                    atomicAdd(&sc[mt * 16 + quad * 4 + i], acc[mt][c][i] * g);
            }
    }
    __syncthreads();
    if (tid < 32) out[(size_t)(b * NN + n) * 16] = sc[tid];
}

// ---------------- launcher ----------------
extern "C" void kernel_launch(void* const* d_in, const int* in_sizes, int n_in,
                              void* d_out, int out_size, void* d_ws, size_t ws_size,
                              hipStream_t stream) {
    const float* coords   = (const float*)d_in[0];
    const float* features = (const float*)d_in[1];
    const float* iW1 = (const float*)d_in[2],  * ib1 = (const float*)d_in[3];
    const float* iW2 = (const float*)d_in[4],  * ib2 = (const float*)d_in[5];
    const float* fW1 = (const float*)d_in[6],  * fb1 = (const float*)d_in[7];
    const float* fW2 = (const float*)d_in[8],  * fb2 = (const float*)d_in[9];
    const float* sW1 = (const float*)d_in[10], * sb1 = (const float*)d_in[11];
    const float* sW2 = (const float*)d_in[12], * sb2 = (const float*)d_in[13];
    const float* gW  = (const float*)d_in[14], * gb  = (const float*)d_in[15];
    float* out = (float*)d_out;

    float* ws = (float*)d_ws;
    float4* coords4 = (float4*)ws;                        // 8*4096 float4 = 512 KB
    float* center = ws + BB * NN * 4;                     // 32 floats
    short* wbf = (short*)((char*)d_ws + 524416);          // 2*90112 shorts = 352 KB

    hipLaunchKernelGGL(k_prep, dim3(BB), dim3(256), 0, stream, coords, coords4, center);
    hipLaunchKernelGGL(k_wprep, dim3(16, 5), dim3(256), 0, stream, iW2, fW1, fW2, sW1, sW2, wbf);
    hipLaunchKernelGGL(k_fused, dim3(1024), dim3(256), 0, stream, coords4, center, features, wbf,
                       iW1, ib1, ib2, fb1, fb2, sb1, sb2, gW, gb, out);
}